// Round 1
// 706.316 us; speedup vs baseline: 1.0041x; 1.0041x over previous
//
#include <hip/hip_runtime.h>
#include <hip/hip_bf16.h>

// ConvLayer: 3x3 s1 p1 conv, x=(256,512,512) f32, W=(3,3,256,256) HWIO, out=(256,512,512) f32.
// Strategy: bf16 implicit GEMM on MFMA (m97 structure).
//   pass1: xt[h][w][ci] = bf16(x[ci][h][w])   via 64KB LDS transpose tile, XOR-swizzled,
//          512-B contiguous global reads, packed ds_write_b64 (4 ci per write)
//   pass2: Wt[kh][kw][co][ci] = bf16(W[kh][kw][ci][co])  + 128B zero line
//   pass3: out[co][h][w] via 128x128 tile, 16x16x32 bf16 MFMA, global_load_lds width16,
//          130-row haloed B tile shared across the 3 kw taps. XCD-banded block swizzle.

typedef __attribute__((ext_vector_type(8))) short bf16x8;
typedef __attribute__((ext_vector_type(4))) float floatx4;

#define HWSZ 262144   // 512*512
#define CIN  256
#define HH   512
#define WWD  512

__device__ __forceinline__ void async_copy16(const void* g, void* l) {
  __builtin_amdgcn_global_load_lds(
      (const __attribute__((address_space(1))) void*)g,
      (__attribute__((address_space(3))) void*)l, 16, 0, 0);
}

// ---------------- pass 1: x f32 [ci][h][w] -> xt bf16 [h][w][ci] ----------------
// grid 2048 = 512 h x 4 w-tiles; block 512 thr. Tile: 128 pixels x 256 ci (128 KB f32 in).
// Phase 1: 512-B contiguous reads along w (4 ci-rows per thread iter), pack 4 bf16
//          (ci..ci+3) -> one ds_write_b64 into swizzled pixel-major LDS.
// Phase 2: conflict-free 16B LDS reads, full 512B pixel rows to global.
// Swizzle (8-B units, u = ci>>2): physical unit = u ^ (2*((p>>2)&15)).
//  - even XOR value keeps 16-B chunk pairing -> phase-2 reads stay uint4
//  - phase-1 b64 writes: 2 lanes/bank (free); phase-2 b128 reads: conflict-free
__global__ __launch_bounds__(512, 4) void convert_x(
    const float* __restrict__ x, __hip_bfloat16* __restrict__ xt)
{
  __shared__ __align__(16) unsigned char lds[128 * 512];  // 64 KB
  const int b  = blockIdx.x;
  const int wt = b & 3;
  const int h  = b >> 2;
  const int w0 = wt << 7;
  const int t  = threadIdx.x;

  // phase 1
  const int wq  = t & 31;        // w quad: pixels p = wq*4 + j
  const int cg  = t >> 5;        // 0..15 : ci unit sub-index
  const int swz = (wq & 15) << 1;
  const float* xbase = x + (size_t)h * WWD + w0 + wq * 4;
#pragma unroll
  for (int it = 0; it < 4; ++it) {
    int s  = it * 16 + cg;       // 4-ci unit index 0..63
    int ci = s << 2;
    float4 v0 = *(const float4*)(xbase + (size_t)(ci + 0) * HWSZ);
    float4 v1 = *(const float4*)(xbase + (size_t)(ci + 1) * HWSZ);
    float4 v2 = *(const float4*)(xbase + (size_t)(ci + 2) * HWSZ);
    float4 v3 = *(const float4*)(xbase + (size_t)(ci + 3) * HWSZ);
#pragma unroll
    for (int j = 0; j < 4; ++j) {
      int p = (wq << 2) + j;
      __hip_bfloat16 b0 = __float2bfloat16(((const float*)&v0)[j]);
      __hip_bfloat16 b1 = __float2bfloat16(((const float*)&v1)[j]);
      __hip_bfloat16 b2 = __float2bfloat16(((const float*)&v2)[j]);
      __hip_bfloat16 b3 = __float2bfloat16(((const float*)&v3)[j]);
      ushort4 u;
      u.x = *(const unsigned short*)&b0;
      u.y = *(const unsigned short*)&b1;
      u.z = *(const unsigned short*)&b2;
      u.w = *(const unsigned short*)&b3;
      *(ushort4*)&lds[p * 512 + ((s ^ swz) << 3)] = u;
    }
  }
  __syncthreads();

  // phase 2: 8 iterations x (16 pixels x 32 chunks)
  const int m  = t & 31;
  const int pq = t >> 5;         // 0..15
#pragma unroll
  for (int it = 0; it < 8; ++it) {
    int p = it * 16 + pq;
    uint4 v = *(const uint4*)&lds[p * 512 + ((m ^ ((p >> 2) & 15)) << 4)];
    *(uint4*)&xt[(((size_t)h * WWD + w0 + p) << 8) + m * 8] = v;
  }
}

// ---------------- pass 2: W f32 [kh][kw][ci][co] -> Wt bf16 [kh][kw][co][ci]; zero line ----
__global__ __launch_bounds__(256) void convert_w(
    const float* __restrict__ Wf, __hip_bfloat16* __restrict__ wt,
    __hip_bfloat16* __restrict__ zb)
{
  const int idx = blockIdx.x * 256 + threadIdx.x;   // < 589824
  const int ci = idx & 255;
  const int co = (idx >> 8) & 255;
  const int kk = idx >> 16;                          // 0..8
  wt[((size_t)(kk * 256 + co) << 8) + ci] =
      __float2bfloat16(Wf[((size_t)(kk * 256 + ci) << 8) + co]);
  if (idx < 64) zb[idx] = __float2bfloat16(0.0f);
}

// ---------------- pass 3: MFMA implicit-GEMM conv ----------------
// grid 4096; block 256 thr = 4 waves (2x2 of 64x64).
// XCD-banded swizzle: xcd = b&7 owns h-band [xcd*64, xcd*64+64); within band,
// wti fastest, then cot, then h -> 6-fold xt row reuse (3kh x 2cot) stays in per-XCD L2.
__global__ __launch_bounds__(256, 3) void conv_mfma(
    const __hip_bfloat16* __restrict__ xt,   // [512][512][256]
    const __hip_bfloat16* __restrict__ wt,   // [9][256][256] (co-major rows, ci contiguous)
    const float* __restrict__ bias,
    float* __restrict__ out,                 // [256][512][512]
    const __hip_bfloat16* __restrict__ zb)
{
  __shared__ __align__(16) __hip_bfloat16 As[3 * 128 * 32];  // [kw][m][k] 24576 B
  __shared__ __align__(16) __hip_bfloat16 Bs[130 * 32];      // [r][k]     8320 B

  const int b     = blockIdx.x;
  const int xcd   = b & 7;
  const int local = b >> 3;            // 0..511
  const int h     = (xcd << 6) + (local >> 3);
  const int rem   = local & 7;
  const int cot   = rem >> 2;
  const int wti   = rem & 3;
  const int w0   = wti << 7;
  const int co0  = cot << 7;
  const int t    = threadIdx.x;
  const int lane = t & 63;
  const int wave = t >> 6;
  const int wm   = wave & 1;    // co half within tile
  const int wn   = wave >> 1;   // w half within tile
  const int mcol = lane & 15;
  const int krow = lane >> 4;

  floatx4 acc[4][4];
#pragma unroll
  for (int mi = 0; mi < 4; ++mi)
#pragma unroll
    for (int ni = 0; ni < 4; ++ni) {
      floatx4 z = {0.f, 0.f, 0.f, 0.f};
      acc[mi][ni] = z;
    }

  for (int kh = 0; kh < 3; ++kh) {
    const int hp = h + kh - 1;
    const bool hok = (unsigned)hp < (unsigned)HH;
    const __hip_bfloat16* xrow = xt + (size_t)hp * (WWD * CIN);

    for (int ci0 = 0; ci0 < CIN; ci0 += 32) {
      __syncthreads();
      // stage A: 3 kw x 128 co-rows x 64 B  = 1536 16B chunks
#pragma unroll
      for (int rnd = 0; rnd < 6; ++rnd) {
        int c  = rnd * 256 + t;
        int kw = c >> 9;
        int m  = (c >> 2) & 127;
        int j  = c & 3;
        const __hip_bfloat16* g =
            wt + (((size_t)((kh * 3 + kw) * 256 + co0 + m)) << 8) + ci0 + (j << 3);
        async_copy16(g, &As[c << 3]);
      }
      // stage B: 130 haloed w-rows x 64 B = 520 chunks
#pragma unroll
      for (int rnd = 0; rnd < 2; ++rnd) {
        int c = rnd * 256 + t;
        int r = c >> 2;
        int j = c & 3;
        int wp = w0 - 1 + r;
        const __hip_bfloat16* g = (hok && (unsigned)wp < (unsigned)WWD)
            ? xrow + ((size_t)wp << 8) + ci0 + (j << 3)
            : zb + (j << 3);
        async_copy16(g, &Bs[c << 3]);
      }
      if (t < 8) {
        int c = 512 + t;
        int r = c >> 2;
        int j = c & 3;
        int wp = w0 - 1 + r;
        const __hip_bfloat16* g = (hok && (unsigned)wp < (unsigned)WWD)
            ? xrow + ((size_t)wp << 8) + ci0 + (j << 3)
            : zb + (j << 3);
        async_copy16(g, &Bs[c << 3]);
      }
      __syncthreads();

#pragma unroll
      for (int kw = 0; kw < 3; ++kw) {
        bf16x8 af[4], bfr[4];
#pragma unroll
        for (int mi = 0; mi < 4; ++mi)
          af[mi] = *(const bf16x8*)&As[(kw << 12) + ((wm * 64 + mi * 16 + mcol) << 5) + (krow << 3)];
#pragma unroll
        for (int ni = 0; ni < 4; ++ni)
          bfr[ni] = *(const bf16x8*)&Bs[((wn * 64 + ni * 16 + mcol + kw) << 5) + (krow << 3)];
#pragma unroll
        for (int mi = 0; mi < 4; ++mi)
#pragma unroll
          for (int ni = 0; ni < 4; ++ni)
            acc[mi][ni] = __builtin_amdgcn_mfma_f32_16x16x32_bf16(
                af[mi], bfr[ni], acc[mi][ni], 0, 0, 0);
      }
    }
  }

  // epilogue: D col = lane&15, row = (lane>>4)*4 + reg (m91-verified)
  const size_t outrow = (size_t)h * WWD;
#pragma unroll
  for (int mi = 0; mi < 4; ++mi) {
#pragma unroll
    for (int r = 0; r < 4; ++r) {
      int co = co0 + wm * 64 + mi * 16 + krow * 4 + r;
      float bv = bias[co];
      float* op = out + (size_t)co * HWSZ + outrow + w0 + wn * 64 + mcol;
#pragma unroll
      for (int ni = 0; ni < 4; ++ni)
        op[ni * 16] = acc[mi][ni][r] + bv;
    }
  }
}

// ---------------- fallback: naive fp32 direct conv (only if ws too small) ----------------
__global__ __launch_bounds__(256) void conv_naive(
    const float* __restrict__ x, const float* __restrict__ Wf,
    const float* __restrict__ bias, float* __restrict__ out)
{
  size_t idx = (size_t)blockIdx.x * 256 + threadIdx.x;
  int w  = (int)(idx & 511);
  int h  = (int)((idx >> 9) & 511);
  int co = (int)(idx >> 18);
  float acc = bias[co];
  for (int kh = 0; kh < 3; ++kh) {
    int hp = h + kh - 1;
    if ((unsigned)hp >= 512u) continue;
    for (int kw = 0; kw < 3; ++kw) {
      int wp = w + kw - 1;
      if ((unsigned)wp >= 512u) continue;
      const float* wcol = Wf + ((size_t)(kh * 3 + kw) << 16) + co;
      const float* xpix = x + (size_t)hp * 512 + wp;
      for (int ci = 0; ci < 256; ++ci)
        acc += xpix[(size_t)ci * HWSZ] * wcol[(size_t)ci << 8];
    }
  }
  out[idx] = acc;
}

extern "C" void kernel_launch(void* const* d_in, const int* in_sizes, int n_in,
                              void* d_out, int out_size, void* d_ws, size_t ws_size,
                              hipStream_t stream) {
  const float* x    = (const float*)d_in[0];
  const float* Wf   = (const float*)d_in[1];
  const float* bias = (const float*)d_in[2];
  float* out = (float*)d_out;

  const size_t xt_bytes = (size_t)HH * WWD * CIN * 2;        // 134217728
  const size_t wt_bytes = (size_t)9 * 256 * 256 * 2;         // 1179648
  const size_t need = xt_bytes + wt_bytes + 256;

  if (ws_size >= need) {
    __hip_bfloat16* xt = (__hip_bfloat16*)d_ws;
    __hip_bfloat16* wt = (__hip_bfloat16*)((char*)d_ws + xt_bytes);
    __hip_bfloat16* zb = (__hip_bfloat16*)((char*)d_ws + xt_bytes + wt_bytes);
    convert_x<<<2048, 512, 0, stream>>>(x, xt);
    convert_w<<<2304, 256, 0, stream>>>(Wf, wt, zb);
    conv_mfma<<<4096, 256, 0, stream>>>(xt, wt, bias, out, zb);
  } else {
    conv_naive<<<262144, 256, 0, stream>>>(x, Wf, bias, out);
  }
}